// Round 6
// baseline (886.798 us; speedup 1.0000x reference)
//
#include <hip/hip_runtime.h>
#include <stdint.h>

// ---------- types / helpers ----------
typedef __attribute__((ext_vector_type(4))) float f32x4;
typedef __attribute__((ext_vector_type(8))) __bf16 bf16x8;
typedef __attribute__((ext_vector_type(8))) unsigned short u16x8;
typedef __attribute__((ext_vector_type(4))) unsigned short u16x4;

typedef const __attribute__((address_space(1))) unsigned int gu32;
typedef __attribute__((address_space(3))) unsigned int lu32;

__device__ __forceinline__ float b2f(unsigned short u) {
  unsigned int x = ((unsigned int)u) << 16;
  float f; __builtin_memcpy(&f, &x, 4); return f;
}
__device__ __forceinline__ unsigned short f2b(float f) {
  unsigned int x; __builtin_memcpy(&x, &f, 4);
  x += 0x7fffu + ((x >> 16) & 1u);           // round-to-nearest-even
  return (unsigned short)(x >> 16);
}

// ---------- f32 -> bf16 transpose: in[R][C] f32 -> out[C][R] bf16 ----------
__global__ __launch_bounds__(256) void transpose_f2b(
    const float* __restrict__ in, unsigned short* __restrict__ out,
    int R, int C) {
  __shared__ unsigned short tile[64][72];
  const int r0 = blockIdx.y * 64, c0 = blockIdx.x * 64;
  const int tid = threadIdx.x;
  const int r = tid >> 3;             // 0..31
  const int c8 = (tid & 7) * 8;       // 0..56
#pragma unroll
  for (int i = 0; i < 2; i++) {
    const float* src = in + (size_t)(r0 + r + 32*i) * C + c0 + c8;
    f32x4 a = *(const f32x4*)src;
    f32x4 b = *(const f32x4*)(src + 4);
    unsigned short tmp[8];
#pragma unroll
    for (int j = 0; j < 4; j++) { tmp[j] = f2b(a[j]); tmp[4+j] = f2b(b[j]); }
    *(u16x8*)(&tile[r + 32*i][c8]) = *(u16x8*)tmp;
  }
  __syncthreads();
#pragma unroll
  for (int i = 0; i < 2; i++) {
    const int ro = r + 32*i;          // output row within tile (= input col)
    unsigned short tmp[8];
#pragma unroll
    for (int j = 0; j < 8; j++) tmp[j] = tile[c8 + j][ro];
    *(u16x8*)(out + (size_t)(c0 + ro) * R + r0 + c8) = *(u16x8*)tmp;
  }
}

// ---------- init h,c to zero ----------
__global__ void init_hc(unsigned short* H, float* C) {
  const int i = blockIdx.x * 256 + threadIdx.x;   // 512*1024 total
  H[i] = 0;
  C[i] = 0.f;
}

// ---------- gather X = [rel|ent], ER = [ent|relation] (f32 in, bf16 out) ----------
__global__ void gather_all(const float* __restrict__ ent,
                           const float* __restrict__ rel,
                           const float* __restrict__ relation,
                           const int* __restrict__ cur, const int* __restrict__ prl,
                           unsigned short* __restrict__ Xall,
                           unsigned short* __restrict__ ERall) {
  const int row = blockIdx.x;          // t*512 + b, 0..4095
  const int b = row & 511;
  const int tid = threadIdx.x;         // 128 threads, each 8 elems of each 1024-row
  const int ci = cur[row], ri = prl[row];
  const float* xsrc = (tid < 64) ? (rel + (size_t)ri * 512 + tid * 8)
                                 : (ent + (size_t)ci * 512 + (tid - 64) * 8);
  const float* esrc = (tid < 64) ? (ent + (size_t)ci * 512 + tid * 8)
                                 : (relation + (size_t)b * 512 + (tid - 64) * 8);
  f32x4 xa = *(const f32x4*)xsrc, xb = *(const f32x4*)(xsrc + 4);
  f32x4 ea = *(const f32x4*)esrc, eb = *(const f32x4*)(esrc + 4);
  unsigned short xt[8], et[8];
#pragma unroll
  for (int j = 0; j < 4; j++) {
    xt[j] = f2b(xa[j]); xt[4+j] = f2b(xb[j]);
    et[j] = f2b(ea[j]); et[4+j] = f2b(eb[j]);
  }
  *(u16x8*)(Xall + (size_t)row * 1024 + tid * 8) = *(u16x8*)xt;
  *(u16x8*)(ERall + (size_t)row * 1024 + tid * 8) = *(u16x8*)et;
}

// ---------- bf16 MFMA GEMM: C = A[M][K] * BT[N][K]^T (+pre)(+bias f32)(relu) ----------
// Staging via global_load_lds width=16 (m97 pattern): LDS linear [128][64],
// chunk c = 4*wave+i covers LDS bytes [c*1024, c*1024+1024); lane l -> byte c*1024+16l
// = row (c*8 + l>>3), col (l&7)*8.  Global source mirrors that mapping per lane.
// BT column index: keff = k < ksplit ? k+koff0 : k+koff1   (64-aligned split)
template<bool HAS_PRE, bool HAS_BIAS, bool DO_RELU, bool OUT_F32>
__global__ __launch_bounds__(256) void gemm_bf16(
    const unsigned short* __restrict__ A, int lda,
    const unsigned short* __restrict__ BT, int ldb,
    int K, int ksplit, int koff0, int koff1,
    const unsigned short* __restrict__ pre,
    const float* __restrict__ bias,
    void* __restrict__ Cout, int ldc) {
  __shared__ unsigned short As[128][64];
  __shared__ unsigned short Bs[128][64];
  const int tid = threadIdx.x;
  const int lane = tid & 63;
  const int w = tid >> 6;
  const int wr = w >> 1, wc = w & 1;               // 2x2 wave grid, 64x64 each
  const int m0 = blockIdx.y * 128, n0 = blockIdx.x * 128;
  f32x4 acc[4][4] = {};
  const int srow = (lane >> 3);                     // 0..7 within chunk
  const int scol = (lane & 7) * 8;                  // 0..56

  for (int k0 = 0; k0 < K; k0 += 64) {
    const int keff = (k0 < ksplit) ? (k0 + koff0) : (k0 + koff1);
#pragma unroll
    for (int i = 0; i < 4; i++) {
      const int c = w * 4 + i;                      // chunk 0..15
      const int row = c * 8 + srow;                 // 0..127
      __builtin_amdgcn_global_load_lds(
          (gu32*)(A + (size_t)(m0 + row) * lda + k0 + scol),
          (lu32*)(&As[0][0] + c * 512), 16, 0, 0);
      __builtin_amdgcn_global_load_lds(
          (gu32*)(BT + (size_t)(n0 + row) * ldb + keff + scol),
          (lu32*)(&Bs[0][0] + c * 512), 16, 0, 0);
    }
    __syncthreads();
#pragma unroll
    for (int ks = 0; ks < 2; ks++) {
      const int kb = ks * 32 + (lane >> 4) * 8;
      bf16x8 af[4], bfr[4];
#pragma unroll
      for (int m = 0; m < 4; m++)
        af[m] = *reinterpret_cast<const bf16x8*>(&As[wr*64 + m*16 + (lane & 15)][kb]);
#pragma unroll
      for (int n = 0; n < 4; n++)
        bfr[n] = *reinterpret_cast<const bf16x8*>(&Bs[wc*64 + n*16 + (lane & 15)][kb]);
#pragma unroll
      for (int m = 0; m < 4; m++)
#pragma unroll
        for (int n = 0; n < 4; n++)
          acc[m][n] = __builtin_amdgcn_mfma_f32_16x16x32_bf16(af[m], bfr[n], acc[m][n], 0, 0, 0);
    }
    __syncthreads();
  }

  // C/D layout: col = lane&15 (n), row = (lane>>4)*4 + r (m)  [verified m89]
  const int cn = lane & 15, rb = (lane >> 4) * 4;
#pragma unroll
  for (int m = 0; m < 4; m++) {
    const int gm = m0 + wr*64 + m*16 + rb;
#pragma unroll
    for (int n = 0; n < 4; n++) {
      const int gn = n0 + wc*64 + n*16 + cn;
#pragma unroll
      for (int r = 0; r < 4; r++) {
        float v = acc[m][n][r];
        if (HAS_PRE)  v += b2f(pre[(size_t)(gm + r) * ldc + gn]);
        if (HAS_BIAS) v += bias[gn];
        if (DO_RELU)  v = v > 0.f ? v : 0.f;
        if (OUT_F32)  ((float*)Cout)[(size_t)(gm + r) * ldc + gn] = v;
        else ((unsigned short*)Cout)[(size_t)(gm + r) * ldc + gn] = f2b(v);
      }
    }
  }
}

// ---------- LSTM gates: z -> c,h ----------
__global__ void lstm_gate(const float* __restrict__ Z,
                          const float* __restrict__ bias,
                          float* __restrict__ C, unsigned short* __restrict__ H) {
  const int idx = blockIdx.x * 256 + threadIdx.x;   // 512*1024
  const int b = idx >> 10, j = idx & 1023;
  const float* zr = Z + (size_t)b * 4096;
  const float i_ = zr[j]        + bias[j];
  const float f_ = zr[1024 + j] + bias[1024 + j];
  const float g_ = zr[2048 + j] + bias[2048 + j];
  const float o_ = zr[3072 + j] + bias[3072 + j];
  const float si = 1.f / (1.f + __expf(-i_));
  const float sf = 1.f / (1.f + __expf(-f_));
  const float so = 1.f / (1.f + __expf(-o_));
  const float c = sf * C[idx] + si * tanhf(g_);
  const float h = so * tanhf(c);
  C[idx] = c;
  H[idx] = f2b(h);
}

// ---------- candidate scoring + softmax: one block per batch row ----------
__global__ __launch_bounds__(256) void score_softmax(
    const unsigned short* __restrict__ F2,   // [512][1024] bf16
    const float* __restrict__ rel,           // [5000][512] f32
    const float* __restrict__ ent,           // [50000][512] f32
    const int* __restrict__ crel, const int* __restrict__ cent, // [512][32] step slice
    float* __restrict__ outp) {              // [512][32] step slice, f32
  const int b = blockIdx.x;
  const int tid = threadIdx.x;
  const int lane = tid & 63, w = tid >> 6;
  __shared__ float feat[1024];
  __shared__ float logits[32];
  {
    u16x4 fv = ((const u16x4*)(F2 + (size_t)b * 1024))[tid];
#pragma unroll
    for (int j = 0; j < 4; j++) feat[tid * 4 + j] = b2f(fv[j]);
  }
  __syncthreads();
  for (int k = w; k < 32; k += 4) {
    const int ri = crel[b * 32 + k], ei = cent[b * 32 + k];
    const float* rp = rel + (size_t)ri * 512 + lane * 8;
    const float* ep = ent + (size_t)ei * 512 + lane * 8;
    f32x4 r0 = *(const f32x4*)rp, r1 = *(const f32x4*)(rp + 4);
    f32x4 e0 = *(const f32x4*)ep, e1 = *(const f32x4*)(ep + 4);
    float sum = 0.f;
#pragma unroll
    for (int j = 0; j < 4; j++) {
      sum += r0[j] * feat[lane * 8 + j];
      sum += r1[j] * feat[lane * 8 + 4 + j];
      sum += e0[j] * feat[512 + lane * 8 + j];
      sum += e1[j] * feat[512 + lane * 8 + 4 + j];
    }
#pragma unroll
    for (int off = 32; off; off >>= 1) sum += __shfl_down(sum, off, 64);
    if (lane == 0) logits[k] = sum;
  }
  __syncthreads();
  if (tid < 32) {
    const float l = logits[tid];
    float mx = l;
#pragma unroll
    for (int off = 16; off; off >>= 1) mx = fmaxf(mx, __shfl_xor(mx, off, 32));
    const float p = __expf(l - mx);
    float s = p;
#pragma unroll
    for (int off = 16; off; off >>= 1) s += __shfl_xor(s, off, 32);
    outp[(size_t)b * 32 + tid] = p / s;
  }
}

// ---------- host launch ----------
extern "C" void kernel_launch(void* const* d_in, const int* in_sizes, int n_in,
                              void* d_out, int out_size, void* d_ws, size_t ws_size,
                              hipStream_t stream) {
  const float* ent      = (const float*)d_in[0];  // [50000][512]
  const float* rel      = (const float*)d_in[1];  // [5000][512]
  const float* relation = (const float*)d_in[2];  // [512][512]
  const float* Wx       = (const float*)d_in[3];  // [1024][4096]
  const float* Wh       = (const float*)d_in[4];  // [1024][4096]
  const float* bvec     = (const float*)d_in[5];  // [4096]
  const float* W1       = (const float*)d_in[6];  // [2048][1536]
  const float* b1       = (const float*)d_in[7];  // [1536]
  const float* W2       = (const float*)d_in[8];  // [1536][1024]
  const float* b2       = (const float*)d_in[9];  // [1024]
  const int* cur  = (const int*)d_in[10];  // [8][512]
  const int* prl  = (const int*)d_in[11];  // [8][512]
  const int* crel = (const int*)d_in[12];  // [8][512][32]
  const int* cent = (const int*)d_in[13];  // [8][512][32]
  float* out = (float*)d_out;              // [8][512][32] f32
  (void)in_sizes; (void)n_in; (void)out_size; (void)ws_size;

  char* wsp = (char*)d_ws;
  auto alloc = [&](size_t bytes) { char* p = wsp; wsp += (bytes + 255) & ~(size_t)255; return p; };
  unsigned short* WxT  = (unsigned short*)alloc((size_t)4096 * 1024 * 2);  // [4096][1024]
  unsigned short* WhT  = (unsigned short*)alloc((size_t)4096 * 1024 * 2);  // [4096][1024]
  unsigned short* W1T  = (unsigned short*)alloc((size_t)1536 * 2048 * 2);  // [1536][2048]
  unsigned short* W2T  = (unsigned short*)alloc((size_t)1024 * 1536 * 2);  // [1024][1536]
  unsigned short* Xall = (unsigned short*)alloc((size_t)4096 * 1024 * 2);  // [8*512][1024]
  unsigned short* ERall= (unsigned short*)alloc((size_t)4096 * 1024 * 2);  // [8*512][1024]
  unsigned short* P1   = (unsigned short*)alloc((size_t)4096 * 4096 * 2);  // [8*512][4096]
  unsigned short* P2   = (unsigned short*)alloc((size_t)4096 * 1536 * 2);  // [8*512][1536]
  float*          Z    = (float*)         alloc((size_t)512 * 4096 * 4);   // [512][4096]
  unsigned short* F1   = (unsigned short*)alloc((size_t)512 * 1536 * 2);   // [512][1536]
  unsigned short* F2   = (unsigned short*)alloc((size_t)512 * 1024 * 2);   // [512][1024]
  unsigned short* H    = (unsigned short*)alloc((size_t)512 * 1024 * 2);   // [512][1024]
  float*          C    = (float*)         alloc((size_t)512 * 1024 * 4);   // [512][1024]

  const dim3 blk(256);
  const int BIG = 1 << 30;

  // one-time (per launch) prep
  transpose_f2b<<<dim3(4096/64, 1024/64), blk, 0, stream>>>(Wx, WxT, 1024, 4096);
  transpose_f2b<<<dim3(4096/64, 1024/64), blk, 0, stream>>>(Wh, WhT, 1024, 4096);
  transpose_f2b<<<dim3(1536/64, 2048/64), blk, 0, stream>>>(W1, W1T, 2048, 1536);
  transpose_f2b<<<dim3(1024/64, 1536/64), blk, 0, stream>>>(W2, W2T, 1536, 1024);
  init_hc<<<2048, 256, 0, stream>>>(H, C);
  gather_all<<<4096, 128, 0, stream>>>(ent, rel, relation, cur, prl, Xall, ERall);

  // recurrence-independent big GEMMs
  // P1 = Xall @ Wx            [4096,4096] k=1024
  gemm_bf16<false,false,false,false><<<dim3(32, 32), blk, 0, stream>>>(
      Xall, 1024, WxT, 1024, 1024, BIG, 0, 0, nullptr, nullptr, P1, 4096);
  // P2 = [ent|relation] @ W1(rows 0..511, 1536..2047)   [4096,1536] k=1024
  gemm_bf16<false,false,false,false><<<dim3(12, 32), blk, 0, stream>>>(
      ERall, 1024, W1T, 2048, 1024, 512, 0, 1024, nullptr, nullptr, P2, 1536);

  for (int t = 0; t < 8; t++) {
    // Z = H @ Wh + P1[t]      [512,4096] k=1024, f32 out
    gemm_bf16<true,false,false,true><<<dim3(32, 4), blk, 0, stream>>>(
        H, 1024, WhT, 1024, 1024, BIG, 0, 0,
        P1 + (size_t)t * 512 * 4096, nullptr, Z, 4096);
    lstm_gate<<<2048, 256, 0, stream>>>(Z, bvec, C, H);
    // F1 = relu(H @ W1(rows 512..1535) + P2[t] + b1)   [512,1536] k=1024
    gemm_bf16<true,true,true,false><<<dim3(12, 4), blk, 0, stream>>>(
        H, 1024, W1T, 2048, 1024, BIG, 512, 0,
        P2 + (size_t)t * 512 * 1536, b1, F1, 1536);
    // F2 = relu(F1 @ W2 + b2)                          [512,1024] k=1536
    gemm_bf16<false,true,true,false><<<dim3(8, 4), blk, 0, stream>>>(
        F1, 1536, W2T, 1536, 1536, BIG, 0, 0, nullptr, b2, F2, 1024);
    score_softmax<<<512, 256, 0, stream>>>(
        F2, rel, ent, crel + (size_t)t * 512 * 32, cent + (size_t)t * 512 * 32,
        out + (size_t)t * 512 * 32);
  }
}

// Round 7
// 384.226 us; speedup vs baseline: 2.3080x; 2.3080x over previous
//
#include <hip/hip_runtime.h>
#include <stdint.h>

// ---------- types / helpers ----------
typedef __attribute__((ext_vector_type(4))) float f32x4;
typedef __attribute__((ext_vector_type(8))) __bf16 bf16x8;
typedef __attribute__((ext_vector_type(8))) unsigned short u16x8;
typedef __attribute__((ext_vector_type(4))) unsigned short u16x4;

__device__ __forceinline__ float b2f(unsigned short u) {
  unsigned int x = ((unsigned int)u) << 16;
  float f; __builtin_memcpy(&f, &x, 4); return f;
}
__device__ __forceinline__ unsigned short f2b(float f) {
  unsigned int x; __builtin_memcpy(&x, &f, 4);
  x += 0x7fffu + ((x >> 16) & 1u);           // round-to-nearest-even
  return (unsigned short)(x >> 16);
}

// ---------- f32 -> bf16 transpose: in[R][C] f32 -> out[C][R] bf16 ----------
__global__ __launch_bounds__(256) void transpose_f2b(
    const float* __restrict__ in, unsigned short* __restrict__ out,
    int R, int C) {
  __shared__ unsigned short tile[64][72];
  const int r0 = blockIdx.y * 64, c0 = blockIdx.x * 64;
  const int tid = threadIdx.x;
  const int r = tid >> 3;             // 0..31
  const int c8 = (tid & 7) * 8;       // 0..56
#pragma unroll
  for (int i = 0; i < 2; i++) {
    const float* src = in + (size_t)(r0 + r + 32*i) * C + c0 + c8;
    f32x4 a = *(const f32x4*)src;
    f32x4 b = *(const f32x4*)(src + 4);
    unsigned short tmp[8];
#pragma unroll
    for (int j = 0; j < 4; j++) { tmp[j] = f2b(a[j]); tmp[4+j] = f2b(b[j]); }
    *(u16x8*)(&tile[r + 32*i][c8]) = *(u16x8*)tmp;
  }
  __syncthreads();
#pragma unroll
  for (int i = 0; i < 2; i++) {
    const int ro = r + 32*i;          // output row within tile (= input col)
    unsigned short tmp[8];
#pragma unroll
    for (int j = 0; j < 8; j++) tmp[j] = tile[c8 + j][ro];
    *(u16x8*)(out + (size_t)(c0 + ro) * R + r0 + c8) = *(u16x8*)tmp;
  }
}

// ---------- init c to zero ----------
__global__ void init_c(float* C) {
  C[blockIdx.x * 256 + threadIdx.x] = 0.f;   // 512*1024 total
}

// ---------- gather X = [rel|ent], ER = [ent|relation] (f32 in, bf16 out) ----------
__global__ void gather_all(const float* __restrict__ ent,
                           const float* __restrict__ rel,
                           const float* __restrict__ relation,
                           const int* __restrict__ cur, const int* __restrict__ prl,
                           unsigned short* __restrict__ Xall,
                           unsigned short* __restrict__ ERall) {
  const int row = blockIdx.x;          // t*512 + b, 0..4095
  const int b = row & 511;
  const int tid = threadIdx.x;         // 128 threads, each 8 elems of each 1024-row
  const int ci = cur[row], ri = prl[row];
  const float* xsrc = (tid < 64) ? (rel + (size_t)ri * 512 + tid * 8)
                                 : (ent + (size_t)ci * 512 + (tid - 64) * 8);
  const float* esrc = (tid < 64) ? (ent + (size_t)ci * 512 + tid * 8)
                                 : (relation + (size_t)b * 512 + (tid - 64) * 8);
  f32x4 xa = *(const f32x4*)xsrc, xb = *(const f32x4*)(xsrc + 4);
  f32x4 ea = *(const f32x4*)esrc, eb = *(const f32x4*)(esrc + 4);
  unsigned short xt[8], et[8];
#pragma unroll
  for (int j = 0; j < 4; j++) {
    xt[j] = f2b(xa[j]); xt[4+j] = f2b(xb[j]);
    et[j] = f2b(ea[j]); et[4+j] = f2b(eb[j]);
  }
  *(u16x8*)(Xall + (size_t)row * 1024 + tid * 8) = *(u16x8*)xt;
  *(u16x8*)(ERall + (size_t)row * 1024 + tid * 8) = *(u16x8*)et;
}

// ---------- bf16 MFMA GEMM, tile MT x 128 (MT in {64,128}) ----------
// C = A[M][K] * BT[N][K]^T (+pre bf16)(+bias f32)(relu).  Reg-staged, padded LDS.
// BT column index: keff = k < ksplit ? k+koff0 : k+koff1   (64-aligned split)
template<int MT, bool HAS_PRE, bool HAS_BIAS, bool DO_RELU, bool OUT_F32>
__global__ __launch_bounds__(256) void gemm_bf16(
    const unsigned short* __restrict__ A, int lda,
    const unsigned short* __restrict__ BT, int ldb,
    int K, int ksplit, int koff0, int koff1,
    const unsigned short* __restrict__ pre,
    const float* __restrict__ bias,
    void* __restrict__ Cout, int ldc) {
  constexpr int MF = MT / 32;                       // M fragments per wave
  __shared__ unsigned short As[MT][72];
  __shared__ unsigned short Bs[128][72];
  const int tid = threadIdx.x;
  const int lane = tid & 63;
  const int w = tid >> 6;
  const int wr = w >> 1, wc = w & 1;                // 2x2 wave grid
  const int m0 = blockIdx.y * MT, n0 = blockIdx.x * 128;
  f32x4 acc[MF][4] = {};
  const int rs = tid >> 3;                          // staging row 0..31
  const int cs = (tid & 7) * 8;                     // staging col chunk

  for (int k0 = 0; k0 < K; k0 += 64) {
    const int keff = (k0 < ksplit) ? (k0 + koff0) : (k0 + koff1);
#pragma unroll
    for (int i = 0; i < MT / 32; i++)
      *(u16x8*)(&As[rs + 32*i][cs]) =
          *(const u16x8*)(A + (size_t)(m0 + rs + 32*i) * lda + k0 + cs);
#pragma unroll
    for (int i = 0; i < 4; i++)
      *(u16x8*)(&Bs[rs + 32*i][cs]) =
          *(const u16x8*)(BT + (size_t)(n0 + rs + 32*i) * ldb + keff + cs);
    __syncthreads();
#pragma unroll
    for (int ks = 0; ks < 2; ks++) {
      const int kb = ks * 32 + (lane >> 4) * 8;
      bf16x8 af[MF], bfr[4];
#pragma unroll
      for (int m = 0; m < MF; m++)
        af[m] = *reinterpret_cast<const bf16x8*>(&As[wr*(MT/2) + m*16 + (lane & 15)][kb]);
#pragma unroll
      for (int n = 0; n < 4; n++)
        bfr[n] = *reinterpret_cast<const bf16x8*>(&Bs[wc*64 + n*16 + (lane & 15)][kb]);
#pragma unroll
      for (int m = 0; m < MF; m++)
#pragma unroll
        for (int n = 0; n < 4; n++)
          acc[m][n] = __builtin_amdgcn_mfma_f32_16x16x32_bf16(af[m], bfr[n], acc[m][n], 0, 0, 0);
    }
    __syncthreads();
  }

  // C/D layout: col = lane&15 (n), row = (lane>>4)*4 + r (m)  [verified m89]
  const int cn = lane & 15, rb = (lane >> 4) * 4;
#pragma unroll
  for (int m = 0; m < MF; m++) {
    const int gm = m0 + wr*(MT/2) + m*16 + rb;
#pragma unroll
    for (int n = 0; n < 4; n++) {
      const int gn = n0 + wc*64 + n*16 + cn;
#pragma unroll
      for (int r = 0; r < 4; r++) {
        float v = acc[m][n][r];
        if (HAS_PRE)  v += b2f(pre[(size_t)(gm + r) * ldc + gn]);
        if (HAS_BIAS) v += bias[gn];
        if (DO_RELU)  v = v > 0.f ? v : 0.f;
        if (OUT_F32)  ((float*)Cout)[(size_t)(gm + r) * ldc + gn] = v;
        else ((unsigned short*)Cout)[(size_t)(gm + r) * ldc + gn] = f2b(v);
      }
    }
  }
}

// ---------- LSTM gates: z (f32 or bf16) -> c, h ----------
template<bool ZF32>
__global__ void lstm_gate(const float* __restrict__ Zf,
                          const unsigned short* __restrict__ Zb,
                          const float* __restrict__ bias,
                          float* __restrict__ C, unsigned short* __restrict__ Hout) {
  const int idx = blockIdx.x * 256 + threadIdx.x;   // 512*1024
  const int b = idx >> 10, j = idx & 1023;
  float i_, f_, g_, o_;
  if (ZF32) {
    const float* zr = Zf + (size_t)b * 4096;
    i_ = zr[j]; f_ = zr[1024 + j]; g_ = zr[2048 + j]; o_ = zr[3072 + j];
  } else {
    const unsigned short* zr = Zb + (size_t)b * 4096;
    i_ = b2f(zr[j]); f_ = b2f(zr[1024 + j]); g_ = b2f(zr[2048 + j]); o_ = b2f(zr[3072 + j]);
  }
  i_ += bias[j]; f_ += bias[1024 + j]; g_ += bias[2048 + j]; o_ += bias[3072 + j];
  const float si = 1.f / (1.f + __expf(-i_));
  const float sf = 1.f / (1.f + __expf(-f_));
  const float so = 1.f / (1.f + __expf(-o_));
  const float c = sf * C[idx] + si * tanhf(g_);
  const float h = so * tanhf(c);
  C[idx] = c;
  Hout[idx] = f2b(h);
}

// ---------- candidate scoring + softmax: one block per (t,b) row ----------
__global__ __launch_bounds__(256) void score_softmax(
    const unsigned short* __restrict__ F2,   // [4096][1024] bf16
    const float* __restrict__ rel,           // [5000][512] f32
    const float* __restrict__ ent,           // [50000][512] f32
    const int* __restrict__ crel, const int* __restrict__ cent, // [4096][32]
    float* __restrict__ outp) {              // [4096][32] f32
  const int b = blockIdx.x;                  // 0..4095
  const int tid = threadIdx.x;
  const int lane = tid & 63, w = tid >> 6;
  __shared__ float feat[1024];
  __shared__ float logits[32];
  {
    u16x4 fv = ((const u16x4*)(F2 + (size_t)b * 1024))[tid];
#pragma unroll
    for (int j = 0; j < 4; j++) feat[tid * 4 + j] = b2f(fv[j]);
  }
  __syncthreads();
  for (int k = w; k < 32; k += 4) {
    const int ri = crel[b * 32 + k], ei = cent[b * 32 + k];
    const float* rp = rel + (size_t)ri * 512 + lane * 8;
    const float* ep = ent + (size_t)ei * 512 + lane * 8;
    f32x4 r0 = *(const f32x4*)rp, r1 = *(const f32x4*)(rp + 4);
    f32x4 e0 = *(const f32x4*)ep, e1 = *(const f32x4*)(ep + 4);
    float sum = 0.f;
#pragma unroll
    for (int j = 0; j < 4; j++) {
      sum += r0[j] * feat[lane * 8 + j];
      sum += r1[j] * feat[lane * 8 + 4 + j];
      sum += e0[j] * feat[512 + lane * 8 + j];
      sum += e1[j] * feat[512 + lane * 8 + 4 + j];
    }
#pragma unroll
    for (int off = 32; off; off >>= 1) sum += __shfl_down(sum, off, 64);
    if (lane == 0) logits[k] = sum;
  }
  __syncthreads();
  if (tid < 32) {
    const float l = logits[tid];
    float mx = l;
#pragma unroll
    for (int off = 16; off; off >>= 1) mx = fmaxf(mx, __shfl_xor(mx, off, 32));
    const float p = __expf(l - mx);
    float s = p;
#pragma unroll
    for (int off = 16; off; off >>= 1) s += __shfl_xor(s, off, 32);
    outp[(size_t)b * 32 + tid] = p / s;
  }
}

// ---------- host launch ----------
extern "C" void kernel_launch(void* const* d_in, const int* in_sizes, int n_in,
                              void* d_out, int out_size, void* d_ws, size_t ws_size,
                              hipStream_t stream) {
  const float* ent      = (const float*)d_in[0];  // [50000][512]
  const float* rel      = (const float*)d_in[1];  // [5000][512]
  const float* relation = (const float*)d_in[2];  // [512][512]
  const float* Wx       = (const float*)d_in[3];  // [1024][4096]
  const float* Wh       = (const float*)d_in[4];  // [1024][4096]
  const float* bvec     = (const float*)d_in[5];  // [4096]
  const float* W1       = (const float*)d_in[6];  // [2048][1536]
  const float* b1       = (const float*)d_in[7];  // [1536]
  const float* W2       = (const float*)d_in[8];  // [1536][1024]
  const float* b2       = (const float*)d_in[9];  // [1024]
  const int* cur  = (const int*)d_in[10];  // [8][512]
  const int* prl  = (const int*)d_in[11];  // [8][512]
  const int* crel = (const int*)d_in[12];  // [8][512][32]
  const int* cent = (const int*)d_in[13];  // [8][512][32]
  float* out = (float*)d_out;              // [8][512][32] f32
  (void)in_sizes; (void)n_in; (void)out_size; (void)ws_size;

  char* wsp = (char*)d_ws;
  auto alloc = [&](size_t bytes) { char* p = wsp; wsp += (bytes + 255) & ~(size_t)255; return p; };
  unsigned short* WxT  = (unsigned short*)alloc((size_t)4096 * 1024 * 2);  // [4096][1024]
  unsigned short* WhT  = (unsigned short*)alloc((size_t)4096 * 1024 * 2);  // [4096][1024]
  unsigned short* W1T  = (unsigned short*)alloc((size_t)1536 * 2048 * 2);  // [1536][2048]
  unsigned short* W2T  = (unsigned short*)alloc((size_t)1024 * 1536 * 2);  // [1024][1536]
  unsigned short* Xall = (unsigned short*)alloc((size_t)4096 * 1024 * 2);  // [8*512][1024]
  unsigned short* ERall= (unsigned short*)alloc((size_t)4096 * 1024 * 2);  // [8*512][1024]
  unsigned short* P1   = (unsigned short*)alloc((size_t)4096 * 4096 * 2);  // [8*512][4096]
  unsigned short* P2   = (unsigned short*)alloc((size_t)4096 * 1536 * 2);  // [8*512][1536]
  float*          Z    = (float*)         alloc((size_t)512 * 4096 * 4);   // [512][4096]
  unsigned short* Hall = (unsigned short*)alloc((size_t)4096 * 1024 * 2);  // [8*512][1024]
  unsigned short* F1   = (unsigned short*)alloc((size_t)4096 * 1536 * 2);  // [8*512][1536]
  unsigned short* F2   = (unsigned short*)alloc((size_t)4096 * 1024 * 2);  // [8*512][1024]
  float*          C    = (float*)         alloc((size_t)512 * 1024 * 4);   // [512][1024]

  const dim3 blk(256);
  const int BIG = 1 << 30;
  const size_t HS = (size_t)512 * 1024;    // per-step H elements

  // one-time (per launch) prep
  transpose_f2b<<<dim3(4096/64, 1024/64), blk, 0, stream>>>(Wx, WxT, 1024, 4096);
  transpose_f2b<<<dim3(4096/64, 1024/64), blk, 0, stream>>>(Wh, WhT, 1024, 4096);
  transpose_f2b<<<dim3(1536/64, 2048/64), blk, 0, stream>>>(W1, W1T, 2048, 1536);
  transpose_f2b<<<dim3(1024/64, 1536/64), blk, 0, stream>>>(W2, W2T, 1536, 1024);
  init_c<<<2048, 256, 0, stream>>>(C);
  gather_all<<<4096, 128, 0, stream>>>(ent, rel, relation, cur, prl, Xall, ERall);

  // recurrence-independent big GEMMs
  // P1 = Xall @ Wx            [4096,4096] k=1024
  gemm_bf16<128,false,false,false,false><<<dim3(32, 32), blk, 0, stream>>>(
      Xall, 1024, WxT, 1024, 1024, BIG, 0, 0, nullptr, nullptr, P1, 4096);
  // P2 = [ent|relation] @ W1(rows 0..511, 1536..2047)   [4096,1536] k=1024
  gemm_bf16<128,false,false,false,false><<<dim3(12, 32), blk, 0, stream>>>(
      ERall, 1024, W1T, 2048, 1024, 512, 0, 1024, nullptr, nullptr, P2, 1536);

  // sequential LSTM chain: only Z-GEMM + gate.  t=0: z = P1[0] (h0 = 0).
  lstm_gate<false><<<2048, 256, 0, stream>>>(nullptr, P1, bvec, C, Hall);
  for (int t = 1; t < 8; t++) {
    // Z = Hall[t-1] @ Wh + P1[t]      [512,4096] k=1024, f32 out, 64x128 tiles
    gemm_bf16<64,true,false,false,true><<<dim3(32, 8), blk, 0, stream>>>(
        Hall + (size_t)(t - 1) * HS, 1024, WhT, 1024, 1024, BIG, 0, 0,
        P1 + (size_t)t * 512 * 4096, nullptr, Z, 4096);
    lstm_gate<true><<<2048, 256, 0, stream>>>(Z, nullptr, bvec, C, Hall + (size_t)t * HS);
  }

  // batched posterior MLP over all 8 steps
  // F1 = relu(Hall @ W1(rows 512..1535) + P2 + b1)   [4096,1536] k=1024
  gemm_bf16<128,true,true,true,false><<<dim3(12, 32), blk, 0, stream>>>(
      Hall, 1024, W1T, 2048, 1024, BIG, 512, 0, P2, b1, F1, 1536);
  // F2 = relu(F1 @ W2 + b2)                          [4096,1024] k=1536
  gemm_bf16<128,false,true,true,false><<<dim3(8, 32), blk, 0, stream>>>(
      F1, 1536, W2T, 1536, 1536, BIG, 0, 0, nullptr, b2, F2, 1024);
  // candidate scoring + softmax for all steps
  score_softmax<<<4096, 256, 0, stream>>>(F2, rel, ent, crel, cent, out);
}